// Round 9
// baseline (17942.603 us; speedup 1.0000x reference)
//
#include <hip/hip_runtime.h>
#include <hip/hip_bf16.h>

// MultilayerGRU: B=128, S=512, H=1024, L=2, O=1024
// Round 9: decoupled chains + all-poll packed flags + swapped MFMA operands
// (A=weights from LDS, B=activations) so epilogue stores are 8B/16B coalesced.
//  - L0 (64 WG): zr@A / g@B, flags L0F, 2 epochs/step
//  - L1zg (128 WG): z@A / g@B (M-half), flags L1GF (1 epoch/step)
//  - L1r+OUT (64 WG): r@A (publish L1RF) / OUT@B with NO wait (slack work)
//  - seq buffers write-once (sc0sc1 -> LLC); consumers use cached loads

typedef __bf16 bf16;
typedef __attribute__((ext_vector_type(8))) __bf16 bf16x8;
typedef __attribute__((ext_vector_type(4))) __bf16 bf16x4;
typedef __attribute__((ext_vector_type(4))) float f32x4;

#define MFMA16(a, b, c) __builtin_amdgcn_mfma_f32_16x16x32_bf16(a, b, c, 0, 0, 0)

static __device__ __forceinline__ bf16x8 ldfrag(const bf16* p) {
  return *reinterpret_cast<const bf16x8*>(p);
}
static __device__ __forceinline__ float sigmf(float x) { return 1.f / (1.f + __expf(-x)); }

// 8B write-through store to LLC
static __device__ __forceinline__ void st8_llc(bf16* p, bf16x4 v) {
  unsigned long long u = __builtin_bit_cast(unsigned long long, v);
  asm volatile("global_store_dwordx2 %0, %1, off sc0 sc1" :: "v"(p), "v"(u) : "memory");
}
// coherent 16B fragment load from LLC (fallback mode for reused rh slots)
static __device__ __forceinline__ bf16x8 ldA_sc(const bf16* p) {
  union { unsigned long long q[2]; bf16x8 v; } u;
  u.q[0] = __hip_atomic_load((const unsigned long long*)p, __ATOMIC_RELAXED,
                             __HIP_MEMORY_SCOPE_AGENT);
  u.q[1] = __hip_atomic_load(((const unsigned long long*)p) + 1, __ATOMIC_RELAXED,
                             __HIP_MEMORY_SCOPE_AGENT);
  return u.v;
}
static __device__ __forceinline__ void spin1(const int* p, int want) {
  while (__hip_atomic_load(p, __ATOMIC_RELAXED, __HIP_MEMORY_SCOPE_AGENT) < want)
    __builtin_amdgcn_s_sleep(1);
}
static __device__ __forceinline__ void publish(int* p, int val) {
  asm volatile("s_waitcnt vmcnt(0)" ::: "memory");
  __syncthreads();
  if (threadIdx.x == 0)
    __hip_atomic_store(p, val, __ATOMIC_RELAXED, __HIP_MEMORY_SCOPE_AGENT);
}

// ---------------- weight cast (layer-0 Wx only, for gx0 GEMM) ----------------
__global__ void k_cast4(const float* __restrict__ s, bf16* __restrict__ d, int n4) {
  int i = blockIdx.x * blockDim.x + threadIdx.x;
  int st = gridDim.x * blockDim.x;
  for (; i < n4; i += st) {
    float4 v = reinterpret_cast<const float4*>(s)[i];
    bf16x4 o = {(bf16)v.x, (bf16)v.y, (bf16)v.z, (bf16)v.w};
    *reinterpret_cast<bf16x4*>(d + (size_t)i * 4) = o;
  }
}

// -------- gx0[s][b][3072] = x @ Wx0^T + bh0 (row-major, round-1 verified) ----
__global__ __launch_bounds__(256) void k_gx0(const float* __restrict__ x,
                                             const bf16* __restrict__ wx0,
                                             const float* __restrict__ bh,
                                             bf16* __restrict__ gx0) {
  const int lane = threadIdx.x & 63;
  const int gw = blockIdx.x * 4 + (threadIdx.x >> 6);
  const int NT = 3072 / 64;  // 48
  const int tm = gw / NT, tn = gw % NT;
  const int m0 = tm * 64, n0 = tn * 64;
  const int r = lane & 15, kq = lane >> 4;
  f32x4 acc[4][4] = {};
  for (int k0 = 0; k0 < 1024; k0 += 32) {
    const int k = k0 + kq * 8;
    bf16x8 a[4], b[4];
#pragma unroll
    for (int mi = 0; mi < 4; ++mi) {
      const int m = m0 + mi * 16 + r;
      const int bb = m & 127, s = m >> 7;
      const float* xp = x + ((size_t)(bb * 512 + s)) * 1024 + k;
      float4 lo = *reinterpret_cast<const float4*>(xp);
      float4 hi = *reinterpret_cast<const float4*>(xp + 4);
      bf16x8 av;
      av[0] = (bf16)lo.x; av[1] = (bf16)lo.y; av[2] = (bf16)lo.z; av[3] = (bf16)lo.w;
      av[4] = (bf16)hi.x; av[5] = (bf16)hi.y; av[6] = (bf16)hi.z; av[7] = (bf16)hi.w;
      a[mi] = av;
    }
#pragma unroll
    for (int ni = 0; ni < 4; ++ni)
      b[ni] = ldfrag(wx0 + (size_t)(n0 + ni * 16 + r) * 1024 + k);
#pragma unroll
    for (int mi = 0; mi < 4; ++mi)
#pragma unroll
      for (int ni = 0; ni < 4; ++ni) acc[mi][ni] = MFMA16(a[mi], b[ni], acc[mi][ni]);
  }
#pragma unroll
  for (int mi = 0; mi < 4; ++mi) {
#pragma unroll
    for (int j = 0; j < 4; ++j) {
      const int m = m0 + mi * 16 + kq * 4 + j;
#pragma unroll
      for (int ni = 0; ni < 4; ++ni) {
        const int col = n0 + ni * 16 + r;
        gx0[(size_t)m * 3072 + col] = (bf16)(acc[mi][ni][j] + bh[col]);
      }
    }
  }
}

// ---------------- persistent GRU scan ----------------
struct GP {
  const float* Wx;
  const float* Wh;
  const float* bh;
  const float* by;
  const float* Why;
  const bf16* gx0;   // [s][b][3072]
  bf16* h0seq;       // 513 x [128][1024] write-once
  bf16* h1seq;       // 513 x
  bf16* rh0seq;      // 512 x (or 2 x fallback)
  bf16* rh1seq;
  float* out;
  int* bar;
  int sc_rh;
};

__device__ __forceinline__ void stage_row8(char* dst, int row, int rb, int k8,
                                           const float* __restrict__ src) {
  const float4 f0 = *reinterpret_cast<const float4*>(src);
  const float4 f1 = *reinterpret_cast<const float4*>(src + 4);
  bf16x8 v;
  v[0] = (bf16)f0.x; v[1] = (bf16)f0.y; v[2] = (bf16)f0.z; v[3] = (bf16)f0.w;
  v[4] = (bf16)f1.x; v[5] = (bf16)f1.y; v[6] = (bf16)f1.z; v[7] = (bf16)f1.w;
  *reinterpret_cast<bf16x8*>(dst + (size_t)row * rb + ((k8 * 2) ^ ((row & 7) << 4))) = v;
}

// Swapped GEMM: A = weight slice (LDS, GT tiles of 16 rows), B = activations
// (global, BT batch tiles of 16). D[oc_local = q*4+j][batch_local = r16].
template <int GT, int BT, int RB, bool SC = false>
__device__ __forceinline__ void mm(const bf16* __restrict__ act, const char* __restrict__ ldsb,
                                   const int kloff, f32x4 (&acc)[GT][BT], const int b0,
                                   const int r16, const int q) {
#pragma unroll 8
  for (int k0 = 0; k0 < 1024; k0 += 32) {
    const int k = k0 + q * 8;
    bf16x8 bfr[BT];
#pragma unroll
    for (int bt = 0; bt < BT; ++bt) {
      const bf16* p = act + (size_t)(b0 + bt * 16 + r16) * 1024 + k;
      bfr[bt] = SC ? ldA_sc(p) : ldfrag(p);
    }
#pragma unroll
    for (int gt = 0; gt < GT; ++gt) {
      const bf16x8 a = *reinterpret_cast<const bf16x8*>(
          ldsb + (size_t)(gt * 16 + r16) * RB + (((kloff + k) * 2) ^ ((r16 & 7) << 4)));
#pragma unroll
      for (int bt = 0; bt < BT; ++bt) acc[gt][bt] = MFMA16(a, bfr[bt], acc[gt][bt]);
    }
  }
}

__global__ void __launch_bounds__(256, 1) k_gru(GP P) {
  extern __shared__ char lds[];
  const int w = blockIdx.x;
  const int tid = threadIdx.x;
  const int r16 = tid & 15, q = (tid >> 4) & 3, wv = tid >> 6;
  const size_t HB = 131072;
  int* L0F = P.bar;         // 64 packed flags
  int* L1GF = P.bar + 64;   // 128
  int* L1RF = P.bar + 192;  // 64

  // ---- role geometry + LDS staging ----
  int role, c0, mh = 0;
  if (w < 64) { role = 0; c0 = w * 16; }
  else if (w < 192) { role = 1; c0 = ((w - 64) >> 1) * 16; mh = (w - 64) & 1; }
  else { role = 2; c0 = (w - 192) * 16; }

  if (role == 0) {
    for (int ch = tid; ch < 32 * 128; ch += 256) {  // rows 0-15 z, 16-31 r, K=1024
      const int row = ch >> 7, k8 = (ch & 127) * 8;
      const int gate = row >> 4, col = c0 + (row & 15);
      stage_row8(lds, row, 2048, k8, P.Wh + ((size_t)(gate * 1024 + col)) * 1024 + k8);
    }
    for (int ch = tid; ch < 16 * 128; ch += 256) {  // g
      const int row = ch >> 7, k8 = (ch & 127) * 8;
      stage_row8(lds + 65536, row, 2048, k8,
                 P.Wh + ((size_t)(2 * 1024 + c0 + row)) * 1024 + k8);
    }
  } else if (role == 1) {
    for (int ch = tid; ch < 16 * 256; ch += 256) {  // z, K=2048 concat [Wx1|Wh1]
      const int row = ch >> 8, k8 = (ch & 255) * 8;
      const int col = c0 + row;
      const float* s = (k8 < 1024) ? P.Wx + ((size_t)(3 * 1024 + col)) * 1024 + k8
                                   : P.Wh + ((size_t)(3 * 1024 + col)) * 1024 + (k8 - 1024);
      stage_row8(lds, row, 4096, k8, s);
    }
    for (int ch = tid; ch < 16 * 256; ch += 256) {  // g
      const int row = ch >> 8, k8 = (ch & 255) * 8;
      const int col = c0 + row;
      const float* s = (k8 < 1024) ? P.Wx + ((size_t)(5 * 1024 + col)) * 1024 + k8
                                   : P.Wh + ((size_t)(5 * 1024 + col)) * 1024 + (k8 - 1024);
      stage_row8(lds + 65536, row, 4096, k8, s);
    }
  } else {
    for (int ch = tid; ch < 16 * 256; ch += 256) {  // r, K=2048
      const int row = ch >> 8, k8 = (ch & 255) * 8;
      const int col = c0 + row;
      const float* s = (k8 < 1024) ? P.Wx + ((size_t)(4 * 1024 + col)) * 1024 + k8
                                   : P.Wh + ((size_t)(4 * 1024 + col)) * 1024 + (k8 - 1024);
      stage_row8(lds, row, 4096, k8, s);
    }
    for (int ch = tid; ch < 16 * 128; ch += 256) {  // Why
      const int row = ch >> 7, k8 = (ch & 127) * 8;
      stage_row8(lds + 65536, row, 2048, k8, P.Why + ((size_t)(c0 + row)) * 1024 + k8);
    }
  }
  __syncthreads();

  float* hid = P.out + (size_t)128 * 512 * 1024;

  if (role == 0) {
    // =================== L0 chain (critical path) ===================
    const int b0 = wv * 32;
    float h0reg[2][4] = {}, z0[2][4];
    bf16x4 pz[2], pr[2], pg[2];
#pragma unroll
    for (int bt = 0; bt < 2; ++bt) {
      const bf16* g0 = P.gx0 + (size_t)(b0 + bt * 16 + r16) * 3072 + c0 + q * 4;
      pz[bt] = *reinterpret_cast<const bf16x4*>(g0);
      pr[bt] = *reinterpret_cast<const bf16x4*>(g0 + 1024);
    }
    for (int t = 0; t < 512; ++t) {
      if (t) {
        if (tid < 64) spin1(L0F + tid, 2 * t);
        __syncthreads();
      }
#pragma unroll
      for (int bt = 0; bt < 2; ++bt)
        pg[bt] = *reinterpret_cast<const bf16x4*>(
            P.gx0 + ((size_t)t * 128 + (b0 + bt * 16 + r16)) * 3072 + 2048 + c0 + q * 4);
      f32x4 acc[2][2] = {};
      mm<2, 2, 2048>(P.h0seq + (size_t)t * HB, lds, 0, acc, b0, r16, q);
      bf16* rh0t = P.rh0seq + (size_t)(P.sc_rh ? (t & 1) : t) * HB;
#pragma unroll
      for (int bt = 0; bt < 2; ++bt) {
        bf16x4 v;
#pragma unroll
        for (int j = 0; j < 4; ++j) {
          z0[bt][j] = sigmf(acc[0][bt][j] + (float)pz[bt][j]);
          const float rv = sigmf(acc[1][bt][j] + (float)pr[bt][j]);
          v[j] = (bf16)(rv * h0reg[bt][j]);
        }
        st8_llc(rh0t + (size_t)(b0 + bt * 16 + r16) * 1024 + c0 + q * 4, v);
      }
      publish(L0F + w, 2 * t + 1);

      if (tid < 64) spin1(L0F + tid, 2 * t + 1);
      __syncthreads();
      if (t + 1 < 512) {
#pragma unroll
        for (int bt = 0; bt < 2; ++bt) {
          const bf16* g0 =
              P.gx0 + ((size_t)(t + 1) * 128 + (b0 + bt * 16 + r16)) * 3072 + c0 + q * 4;
          pz[bt] = *reinterpret_cast<const bf16x4*>(g0);
          pr[bt] = *reinterpret_cast<const bf16x4*>(g0 + 1024);
        }
      }
      f32x4 ac2[1][2] = {};
      if (P.sc_rh) mm<1, 2, 2048, true>(rh0t, lds + 65536, 0, ac2, b0, r16, q);
      else mm<1, 2, 2048, false>(rh0t, lds + 65536, 0, ac2, b0, r16, q);
#pragma unroll
      for (int bt = 0; bt < 2; ++bt) {
        bf16x4 v;
#pragma unroll
        for (int j = 0; j < 4; ++j) {
          const float gv = tanhf(ac2[0][bt][j] + (float)pg[bt][j]);
          const float hn = z0[bt][j] * h0reg[bt][j] + (1.f - z0[bt][j]) * gv;
          h0reg[bt][j] = hn;
          v[j] = (bf16)hn;
        }
        st8_llc(P.h0seq + (size_t)(t + 1) * HB + (size_t)(b0 + bt * 16 + r16) * 1024 + c0 + q * 4,
                v);
      }
      publish(L0F + w, 2 * t + 2);
    }
#pragma unroll
    for (int bt = 0; bt < 2; ++bt) {
      f32x4 hv;
#pragma unroll
      for (int j = 0; j < 4; ++j) hv[j] = h0reg[bt][j];
      *reinterpret_cast<f32x4*>(hid + (size_t)(b0 + bt * 16 + r16) * 2048 + c0 + q * 4) = hv;
    }
  } else if (role == 1) {
    // =================== L1 z/g chain ===================
    const int idx = w - 64;
    const int b0 = mh * 64 + wv * 16;
    float h1reg[4] = {}, z1[4];
    const float4 bzv = *reinterpret_cast<const float4*>(P.bh + 3072 + c0 + q * 4);
    const float4 bgv = *reinterpret_cast<const float4*>(P.bh + 5120 + c0 + q * 4);
    const float* bz = reinterpret_cast<const float*>(&bzv);
    const float* bg = reinterpret_cast<const float*>(&bgv);
    for (int t = 0; t < 512; ++t) {
      {
        const int* fp = nullptr;
        int want = 0;
        if (tid < 64) { fp = L0F + tid; want = 2 * t + 2; }
        else if (tid < 192) { fp = L1GF + (tid - 64); want = t; }
        if (fp && want > 0) spin1(fp, want);
        __syncthreads();
      }
      f32x4 acc[1][1] = {};
      mm<1, 1, 4096>(P.h0seq + (size_t)(t + 1) * HB, lds, 0, acc, b0, r16, q);
      mm<1, 1, 4096>(P.h1seq + (size_t)t * HB, lds, 1024, acc, b0, r16, q);
#pragma unroll
      for (int j = 0; j < 4; ++j) z1[j] = sigmf(acc[0][0][j] + bz[j]);

      if (tid < 64) spin1(L1RF + tid, t + 1);
      __syncthreads();
      bf16* rh1t = P.rh1seq + (size_t)(P.sc_rh ? (t & 1) : t) * HB;
      f32x4 ac2[1][1] = {};
      mm<1, 1, 4096>(P.h0seq + (size_t)(t + 1) * HB, lds + 65536, 0, ac2, b0, r16, q);
      if (P.sc_rh) mm<1, 1, 4096, true>(rh1t, lds + 65536, 1024, ac2, b0, r16, q);
      else mm<1, 1, 4096, false>(rh1t, lds + 65536, 1024, ac2, b0, r16, q);
      bf16x4 v;
#pragma unroll
      for (int j = 0; j < 4; ++j) {
        const float gv = tanhf(ac2[0][0][j] + bg[j]);
        const float hn = z1[j] * h1reg[j] + (1.f - z1[j]) * gv;
        h1reg[j] = hn;
        v[j] = (bf16)hn;
      }
      st8_llc(P.h1seq + (size_t)(t + 1) * HB + (size_t)(b0 + r16) * 1024 + c0 + q * 4, v);
      publish(L1GF + idx, t + 1);
    }
    f32x4 hv;
#pragma unroll
    for (int j = 0; j < 4; ++j) hv[j] = h1reg[j];
    *reinterpret_cast<f32x4*>(hid + (size_t)(b0 + r16) * 2048 + 1024 + c0 + q * 4) = hv;
  } else {
    // =================== L1 r + OUT (slack) ===================
    const int b0 = wv * 32;
    const float4 brv = *reinterpret_cast<const float4*>(P.bh + 4096 + c0 + q * 4);
    const float4 byv = *reinterpret_cast<const float4*>(P.by + c0 + q * 4);
    const float* br = reinterpret_cast<const float*>(&brv);
    const float* by = reinterpret_cast<const float*>(&byv);
    for (int t = 0; t < 512; ++t) {
      {
        const int* fp = nullptr;
        int want = 0;
        if (tid < 64) { fp = L0F + tid; want = 2 * t + 2; }
        else if (tid < 192) { fp = L1GF + (tid - 64); want = t; }
        if (fp && want > 0) spin1(fp, want);
        __syncthreads();
      }
      bf16x4 h1p[2];
#pragma unroll
      for (int bt = 0; bt < 2; ++bt)
        h1p[bt] = *reinterpret_cast<const bf16x4*>(
            P.h1seq + (size_t)t * HB + (size_t)(b0 + bt * 16 + r16) * 1024 + c0 + q * 4);
      f32x4 acc[1][2] = {};
      mm<1, 2, 4096>(P.h0seq + (size_t)(t + 1) * HB, lds, 0, acc, b0, r16, q);
      mm<1, 2, 4096>(P.h1seq + (size_t)t * HB, lds, 1024, acc, b0, r16, q);
      bf16* rh1t = P.rh1seq + (size_t)(P.sc_rh ? (t & 1) : t) * HB;
#pragma unroll
      for (int bt = 0; bt < 2; ++bt) {
        bf16x4 v;
#pragma unroll
        for (int j = 0; j < 4; ++j) {
          const float rv = sigmf(acc[0][bt][j] + br[j]);
          v[j] = (bf16)(rv * (float)h1p[bt][j]);
        }
        st8_llc(rh1t + (size_t)(b0 + bt * 16 + r16) * 1024 + c0 + q * 4, v);
      }
      publish(L1RF + (w - 192), t + 1);

      if (t >= 1) {  // OUT: y[t-1] = h1seq[t] @ Why^T + by  (no wait: already gated)
        f32x4 ac2[1][2] = {};
        mm<1, 2, 2048>(P.h1seq + (size_t)t * HB, lds + 65536, 0, ac2, b0, r16, q);
#pragma unroll
        for (int bt = 0; bt < 2; ++bt) {
          f32x4 ov;
#pragma unroll
          for (int j = 0; j < 4; ++j) ov[j] = ac2[0][bt][j] + by[j];
          *reinterpret_cast<f32x4*>(
              P.out + ((size_t)(b0 + bt * 16 + r16) * 512 + (t - 1)) * 1024 + c0 + q * 4) = ov;
        }
      }
    }
    // tail: y[511] from h1seq[512]
    if (tid < 128) spin1(L1GF + tid, 512);
    __syncthreads();
    f32x4 ac2[1][2] = {};
    mm<1, 2, 2048>(P.h1seq + (size_t)512 * HB, lds + 65536, 0, ac2, b0, r16, q);
#pragma unroll
    for (int bt = 0; bt < 2; ++bt) {
      f32x4 ov;
#pragma unroll
      for (int j = 0; j < 4; ++j) ov[j] = ac2[0][bt][j] + by[j];
      *reinterpret_cast<f32x4*>(
          P.out + ((size_t)(b0 + bt * 16 + r16) * 512 + 511) * 1024 + c0 + q * 4) = ov;
    }
  }
}

extern "C" void kernel_launch(void* const* d_in, const int* in_sizes, int n_in,
                              void* d_out, int out_size, void* d_ws, size_t ws_size,
                              hipStream_t stream) {
  const float* x = (const float*)d_in[0];
  const float* Wx = (const float*)d_in[1];
  const float* Wh = (const float*)d_in[2];
  const float* bh = (const float*)d_in[3];
  const float* Why = (const float*)d_in[4];
  const float* by = (const float*)d_in[5];
  float* out = (float*)d_out;

  const size_t HBb = (size_t)131072 * 2;
  auto al = [](size_t v) { return (v + 255) & ~(size_t)255; };
  const size_t szWxb = al((size_t)3 * 1024 * 1024 * 2);
  const size_t szGx = al((size_t)512 * 128 * 3072 * 2);
  const size_t szHseq = al((size_t)513 * HBb);
  const size_t szRhFull = al((size_t)512 * HBb);
  const size_t szRhPar = al((size_t)2 * HBb);
  const size_t szBar = 4096;
  const size_t needFull = szWxb + szGx + 2 * szHseq + 2 * szRhFull + szBar;
  const int sc_rh = (ws_size >= needFull) ? 0 : 1;
  const size_t szRh = sc_rh ? szRhPar : szRhFull;

  char* ws = (char*)d_ws;
  size_t off = 0;
  auto alloc = [&](size_t bytes) -> void* {
    void* p = ws + off;
    off += bytes;
    return p;
  };
  bf16* Wxb = (bf16*)alloc(szWxb);
  bf16* gx0 = (bf16*)alloc(szGx);
  bf16* h0seq = (bf16*)alloc(szHseq);
  bf16* h1seq = (bf16*)alloc(szHseq);
  bf16* rh0seq = (bf16*)alloc(szRh);
  bf16* rh1seq = (bf16*)alloc(szRh);
  int* bar = (int*)alloc(szBar);

  hipFuncSetAttribute((const void*)k_gru, hipFuncAttributeMaxDynamicSharedMemorySize, 131072);

  k_cast4<<<512, 256, 0, stream>>>(Wx, Wxb, (3 * 1024 * 1024) / 4);
  hipMemsetAsync(h0seq, 0, 262144, stream);  // h0seq[0] = 0
  hipMemsetAsync(h1seq, 0, 262144, stream);  // h1seq[0] = 0
  hipMemsetAsync(bar, 0, szBar, stream);

  k_gx0<<<12288, 256, 0, stream>>>(x, Wxb, bh, gx0);

  GP gp{Wx, Wh, bh, by, Why, gx0, h0seq, h1seq, rh0seq, rh1seq, out, bar, sc_rh};
  void* kargs[] = {&gp};
  hipLaunchCooperativeKernel((void*)k_gru, dim3(256), dim3(256), kargs, 131072, stream);
}